// Round 2
// baseline (61.688 us; speedup 1.0000x reference)
//
#include <hip/hip_runtime.h>
#include <math.h>

#define NIMG 16
#define H 512
#define W 512
#define ORI 10
#define LDS_S 67   // odd stride: bank aliasing <=2-way (free)

// ---------------- Kernel 1: per-cell 10-bin HOG histograms ----------------
// grid (8,8,16), block 256. Each block: 64x64 pixel tile = 8x8 cells.
// 4 threads per cell, each does 2 pixel rows. Histograms accumulate via
// LDS ds_add_f32 (overlaps with VALU across waves); bin index from exact
// cross-product comparisons (no atan2, no division, no int mod).
__global__ __launch_bounds__(256) void hog_cells_k(const float* __restrict__ img,
                                                   float* __restrict__ cells) {
    __shared__ float tile[66 * LDS_S];
    __shared__ float hist[64 * 11];      // per-cell 10 bins, stride 11 (pad)
    const int n = blockIdx.z;
    const int ty0 = blockIdx.y * 64;
    const int tx0 = blockIdx.x * 64;
    const float* im = img + (size_t)n * (H * W);
    const int tid = threadIdx.x;

    for (int i = tid; i < 64 * 11; i += 256) hist[i] = 0.0f;

    // stage 66x66 halo (zero padding outside image)
    for (int i = tid; i < 66 * 66; i += 256) {
        int r = i / 66, c = i - r * 66;
        int gy = ty0 + r - 1, gx = tx0 + c - 1;
        float v = 0.0f;
        if ((unsigned)gy < (unsigned)H && (unsigned)gx < (unsigned)W)
            v = im[gy * W + gx];
        tile[r * LDS_S + c] = v;
    }
    __syncthreads();

    const int cell = tid >> 2;        // 0..63
    const int sub  = tid & 3;         // 0..3 -> rows 2*sub, 2*sub+1 of the cell
    const int cy = cell >> 3, cx = cell & 7;
    const int py0 = cy * 8 + sub * 2;
    const int px0 = cx * 8;

    float w[4][10];
    #pragma unroll
    for (int r = 0; r < 4; ++r)
        #pragma unroll
        for (int c = 0; c < 10; ++c)
            w[r][c] = tile[(py0 + r) * LDS_S + (px0 + c)];

    float* hcell = &hist[cell * 11];

    #pragma unroll
    for (int rr = 0; rr < 2; ++rr) {
        #pragma unroll
        for (int j = 0; j < 8; ++j) {
            // correlation (XLA conv does not flip kernels)
            float gx = (w[rr  ][j] - w[rr  ][j+2])
                     + 2.0f * (w[rr+1][j] - w[rr+1][j+2])
                     + (w[rr+2][j] - w[rr+2][j+2]);
            float gy = (w[rr  ][j] + 2.0f * w[rr  ][j+1] + w[rr  ][j+2])
                     - (w[rr+2][j] + 2.0f * w[rr+2][j+1] + w[rr+2][j+2]);
            float mag = __builtin_amdgcn_sqrtf(gx * gx + gy * gy);

            // bin = floor(atan2(gx,gy)/pi*10) mod 10 — invariant under theta+pi,
            // so fold to upper half-plane (y>=0), reflect into first quadrant,
            // and count how many bin boundaries (k*pi/10, k=1..4) we passed.
            float y  = fabsf(gx);                      // sin component, >= 0
            float x  = (gx < 0.0f) ? -gy : gy;         // cos component
            float x2 = fabsf(x);
            int fm2 = 0;
            fm2 += (y * 0.95105652f >= x2 * 0.30901699f);  // phi2 >= 1*pi/10
            fm2 += (y * 0.80901699f >= x2 * 0.58778525f);  // phi2 >= 2*pi/10
            fm2 += (y * 0.58778525f >= x2 * 0.80901699f);  // phi2 >= 3*pi/10
            fm2 += (y * 0.30901699f >= x2 * 0.95105652f);  // phi2 >= 4*pi/10
            int fm = (x < 0.0f) ? (9 - fm2) : fm2;
            int cm = fm + 1;
            cm = (cm == 10) ? 0 : cm;
            // exact-integer-p cases of the reference (floor==ceil):
            //   gx==0 -> p in {0,10}  -> bin 0 gets mag + (1-mag)
            //   gy==0 -> p in {-5,5}  -> bin 5 gets mag + (1-mag)
            if (gx == 0.0f)      { fm = 0; cm = 0; }
            else if (gy == 0.0f) { fm = 5; cm = 5; }

            atomicAdd(hcell + fm, mag);          // ds_add_f32
            atomicAdd(hcell + cm, 1.0f - mag);
        }
    }

    __syncthreads();

    // write cell means: 640 values per block
    const int gcy0 = blockIdx.y * 8;
    const int gcx0 = blockIdx.x * 8;
    for (int i = tid; i < 64 * ORI; i += 256) {
        int b  = i >> 6;          // 0..9
        int cl = i & 63;
        int cyy = cl >> 3, cxx = cl & 7;
        float v = hist[cl * 11 + b] * 0.015625f;
        cells[(((size_t)n * ORI + b) * 64 + gcy0 + cyy) * 64 + (gcx0 + cxx)] = v;
    }
}

// ---------------- Kernel 2: 2x2 block gather + L2 normalize ----------------
// one thread per (n, o, br, bc); writes 4 consecutive outputs as float4
__global__ __launch_bounds__(256) void hog_blocks_k(const float* __restrict__ cells,
                                                    float* __restrict__ out) {
    const int total = NIMG * ORI * 63 * 63;
    int idx = blockIdx.x * blockDim.x + threadIdx.x;
    if (idx >= total) return;
    int bc = idx % 63;
    int t  = idx / 63;
    int br = t % 63;
    int no = t / 63;                       // n*ORI + o
    const float* c = cells + (((size_t)no * 64 + br) * 64 + bc);
    float c00 = c[0], c01 = c[1], c10 = c[64], c11 = c[65];
    float s = ((c00 + c01) + (c10 + c11));
    float denom = sqrtf(s * s + 1e-10f);   // sqrt(sum^2 + EPS^2)
    float inv = 1.0f / denom;              // one IEEE divide, then 4 muls
    float4 o;
    o.x = c00 * inv;
    o.y = c01 * inv;
    o.z = c10 * inv;
    o.w = c11 * inv;
    reinterpret_cast<float4*>(out)[idx] = o;
}

extern "C" void kernel_launch(void* const* d_in, const int* in_sizes, int n_in,
                              void* d_out, int out_size, void* d_ws, size_t ws_size,
                              hipStream_t stream) {
    (void)in_sizes; (void)n_in; (void)out_size; (void)ws_size;
    const float* img = (const float*)d_in[0];   // (16,1,512,512)
    // d_in[1] is the fixed sobel weight pair; constants are baked into kernel 1
    float* out   = (float*)d_out;               // (16, 10*63*63*2*2) f32
    float* cells = (float*)d_ws;                // (16,10,64,64) f32 scratch

    hog_cells_k<<<dim3(8, 8, NIMG), 256, 0, stream>>>(img, cells);

    const int total = NIMG * ORI * 63 * 63;
    hog_blocks_k<<<(total + 255) / 256, 256, 0, stream>>>(cells, out);
}

// Round 3
// 26.145 us; speedup vs baseline: 2.3595x; 2.3595x over previous
//
#include <hip/hip_runtime.h>
#include <math.h>

#define NIMG 16
#define H 512
#define W 512
#define ORI 10
#define LDS_S 67   // odd stride: bank aliasing <=2-way (free)

// ---------------- Kernel 1: per-cell 10-bin HOG histograms ----------------
// grid (8,8,16), block 256. Each block: 64x64 pixel tile = 8x8 cells.
// 4 threads per cell, 2 pixel rows each. Register-resident CUMULATIVE
// histogram T[11]; bin index never materialized — 9 cross-product sign
// tests give e_j = (bin >= j) directly. No atomics, no atan2, no division.
__global__ __launch_bounds__(256) void hog_cells_k(const float* __restrict__ img,
                                                   float* __restrict__ cells) {
    __shared__ float tile[66 * LDS_S];
    __shared__ float hist[64 * 11];      // per-cell bins staging (stride 11)
    const int n = blockIdx.z;
    const int ty0 = blockIdx.y * 64;
    const int tx0 = blockIdx.x * 64;
    const float* im = img + (size_t)n * (H * W);
    const int tid = threadIdx.x;

    // stage 66x66 halo (zero padding outside image)
    for (int i = tid; i < 66 * 66; i += 256) {
        int r = i / 66, c = i - r * 66;
        int gy = ty0 + r - 1, gx = tx0 + c - 1;
        float v = 0.0f;
        if ((unsigned)gy < (unsigned)H && (unsigned)gx < (unsigned)W)
            v = im[gy * W + gx];
        tile[r * LDS_S + c] = v;
    }
    __syncthreads();

    const int cell = tid >> 2;        // 0..63
    const int sub  = tid & 3;         // rows 2*sub, 2*sub+1 of the cell
    const int cy = cell >> 3, cx = cell & 7;
    const int py0 = cy * 8 + sub * 2;
    const int px0 = cx * 8;

    float w[4][10];
    #pragma unroll
    for (int r = 0; r < 4; ++r)
        #pragma unroll
        for (int c = 0; c < 10; ++c)
            w[r][c] = tile[(py0 + r) * LDS_S + (px0 + c)];

    float T[11];
    #pragma unroll
    for (int j = 0; j < 11; ++j) T[j] = 0.0f;

    #pragma unroll
    for (int rr = 0; rr < 2; ++rr) {
        // column-factored Sobel: t = [1,2,1] vertical, u = top - bottom
        float t[10], u[10];
        #pragma unroll
        for (int c = 0; c < 10; ++c) {
            t[c] = w[rr][c] + 2.0f * w[rr+1][c] + w[rr+2][c];
            u[c] = w[rr][c] - w[rr+2][c];
        }
        #pragma unroll
        for (int j = 0; j < 8; ++j) {
            float gx = t[j] - t[j+2];
            float gy = u[j] + 2.0f * u[j+1] + u[j+2];
            float mag = __builtin_amdgcn_sqrtf(gx * gx + gy * gy);
            float wB = 1.0f - mag;
            bool gx0 = (gx == 0.0f);
            bool gy0 = (gy == 0.0f);
            if (gx0 | gy0) wB = 0.0f;   // exact-integer-p: floor==ceil -> bin gets 1.0
            float yv = fabsf(gx);                    // sin component >= 0
            float xv = (gx < 0.0f) ? -gy : gy;       // folded cos component
            if (gx0) xv = 1.0f;                      // force all e false -> bin0 += 1
            // e_j = (bin >= j) <=> sin(phi - j*pi/10) >= 0, phi in [0, pi)
            bool e1 = (yv *  0.9510565163f - xv * 0.3090169944f >= 0.0f);
            bool e2 = (yv *  0.8090169944f - xv * 0.5877852523f >= 0.0f);
            bool e3 = (yv *  0.5877852523f - xv * 0.8090169944f >= 0.0f);
            bool e4 = (yv *  0.3090169944f - xv * 0.9510565163f >= 0.0f);
            bool e5 = (xv <= 0.0f);                  // cos(pi/2)=0 exactly
            bool e6 = (yv * -0.3090169944f - xv * 0.9510565163f >= 0.0f);
            bool e7 = (yv * -0.5877852523f - xv * 0.8090169944f >= 0.0f);
            bool e8 = (yv * -0.8090169944f - xv * 0.5877852523f >= 0.0f);
            bool e9 = (yv * -0.9510565163f - xv * 0.3090169944f >= 0.0f);
            // cumulative: slots <= bin get mag+(1-mag)=1; slot bin+1 gets (1-mag)
            T[0]  += 1.0f;
            T[1]  += e1 ? 1.0f : wB;
            T[2]  += e2 ? 1.0f : (e1 ? wB : 0.0f);
            T[3]  += e3 ? 1.0f : (e2 ? wB : 0.0f);
            T[4]  += e4 ? 1.0f : (e3 ? wB : 0.0f);
            T[5]  += e5 ? 1.0f : (e4 ? wB : 0.0f);
            T[6]  += e6 ? 1.0f : (e5 ? wB : 0.0f);
            T[7]  += e7 ? 1.0f : (e6 ? wB : 0.0f);
            T[8]  += e8 ? 1.0f : (e7 ? wB : 0.0f);
            T[9]  += e9 ? 1.0f : (e8 ? wB : 0.0f);
            T[10] += e9 ? wB : 0.0f;                 // ceil wrap: slot10 -> bin0
        }
    }

    // cumulative -> bins, then 4-lane shuffle reduce
    float b[10];
    #pragma unroll
    for (int j = 0; j < 10; ++j) b[j] = T[j] - T[j + 1];
    b[0] += T[10];
    #pragma unroll
    for (int j = 0; j < 10; ++j) {
        float v = b[j];
        v += __shfl_xor(v, 1);
        v += __shfl_xor(v, 2);
        b[j] = v;
    }
    if (sub == 0) {
        #pragma unroll
        for (int j = 0; j < 10; ++j) hist[cell * 11 + j] = b[j];
    }
    __syncthreads();

    // coalesced cell-mean writes: 640 values per block
    const int gcy0 = blockIdx.y * 8;
    const int gcx0 = blockIdx.x * 8;
    for (int i = tid; i < 64 * ORI; i += 256) {
        int bb = i >> 6;          // 0..9
        int cl = i & 63;
        int cyy = cl >> 3, cxx = cl & 7;
        float v = hist[cl * 11 + bb] * 0.015625f;
        cells[(((size_t)n * ORI + bb) * 64 + gcy0 + cyy) * 64 + (gcx0 + cxx)] = v;
    }
}

// ---------------- Kernel 2: 2x2 block gather + L2 normalize ----------------
__global__ __launch_bounds__(256) void hog_blocks_k(const float* __restrict__ cells,
                                                    float* __restrict__ out) {
    const int total = NIMG * ORI * 63 * 63;
    int idx = blockIdx.x * blockDim.x + threadIdx.x;
    if (idx >= total) return;
    int bc = idx % 63;
    int t  = idx / 63;
    int br = t % 63;
    int no = t / 63;                       // n*ORI + o
    const float* c = cells + (((size_t)no * 64 + br) * 64 + bc);
    float c00 = c[0], c01 = c[1], c10 = c[64], c11 = c[65];
    float s = ((c00 + c01) + (c10 + c11));
    float denom = sqrtf(s * s + 1e-10f);   // sqrt(sum^2 + EPS^2)
    float inv = 1.0f / denom;              // one IEEE divide, then 4 muls
    float4 o;
    o.x = c00 * inv;
    o.y = c01 * inv;
    o.z = c10 * inv;
    o.w = c11 * inv;
    reinterpret_cast<float4*>(out)[idx] = o;
}

extern "C" void kernel_launch(void* const* d_in, const int* in_sizes, int n_in,
                              void* d_out, int out_size, void* d_ws, size_t ws_size,
                              hipStream_t stream) {
    (void)in_sizes; (void)n_in; (void)out_size; (void)ws_size;
    const float* img = (const float*)d_in[0];   // (16,1,512,512)
    float* out   = (float*)d_out;               // (16, 10*63*63*2*2) f32
    float* cells = (float*)d_ws;                // (16,10,64,64) f32 scratch

    hog_cells_k<<<dim3(8, 8, NIMG), 256, 0, stream>>>(img, cells);

    const int total = NIMG * ORI * 63 * 63;
    hog_blocks_k<<<(total + 255) / 256, 256, 0, stream>>>(cells, out);
}